// Round 5
// baseline (409.703 us; speedup 1.0000x reference)
//
#include <hip/hip_runtime.h>
#include <math.h>

constexpr int NN = 4096, DD = 64, TT = 60, HH = 128, GG = 512, KK = 192;

typedef _Float16 h8 __attribute__((ext_vector_type(8)));
typedef float f4 __attribute__((ext_vector_type(4)));

// ws layout (float offsets)
constexpr size_t XNT = 0;                                  // half [T][N][D]; REUSED later as swizzled hbn16
constexpr size_t WFRG = (size_t)TT * NN * DD / 2;          // half [w][g][ks][lane][8] = 98304 halves
constexpr size_t BSUM = WFRG + 98304 / 2;                  // [512] f32
constexpr size_t SC1 = BSUM + GG;                          // [64]
constexpr size_t SH1 = SC1 + DD;                           // [64]
constexpr size_t HID = SH1 + DD;                           // [N][H] f32
constexpr size_t HBN = HID + (size_t)NN * HH;              // [N][H]
constexpr size_t SC2 = HBN + (size_t)NN * HH;              // [128]
constexpr size_t SH2 = SC2 + HH;
constexpr size_t U1O = SH2 + HH;
constexpr size_t U2O = U1O + HH;
constexpr size_t CCO = U2O + HH;                           // [4]: c1, c2, s1max(encoded uint)
constexpr size_t S1O = CCO + 4;                            // [N]
constexpr size_t S2O = S1O + NN;
constexpr size_t H2O = S2O + NN;                           // [N][H]
constexpr size_t SSUM = H2O + (size_t)NN * HH;             // [0:64) bn1 sum, [64:128) bn1 sumsq,
                                                           // 128 bn1 ctr, 129 bn2 ctr,
                                                           // [132:260) bn2 sum, [260:388) bn2 sumsq

__device__ __forceinline__ float sigmoidf_(float x) { return 1.f / (1.f + __expf(-x)); }
__device__ __forceinline__ float tanhfast_(float x) { return 1.f - 2.f / (__expf(2.f * x) + 1.f); }
__device__ __forceinline__ float leakyf_(float z) { return fmaxf(z, 0.01f * z); }

// monotone float<->uint encoding for atomicMax over signed floats
__device__ __forceinline__ unsigned fenc_(float f) {
    unsigned b = __float_as_uint(f);
    return (b & 0x80000000u) ? ~b : (b | 0x80000000u);
}
__device__ __forceinline__ float fdec_(unsigned u) {
    return (u & 0x80000000u) ? __uint_as_float(u & 0x7fffffffu) : __uint_as_float(~u);
}

// ---- prep (fused): weight swizzle + bias sum + zero accums | block 384: u/v vectors ----
// frag (w,g,ks): value = W[k][col], col = g*128 + w*16 + (lane&15), k = ks*32 + (lane>>4)*8 + j
__global__ void k_prep(const float* __restrict__ Wih, const float* __restrict__ Whh,
                       const float* __restrict__ bih, const float* __restrict__ bhh,
                       const float* __restrict__ Wt, const float* __restrict__ bt,
                       const float* __restrict__ a, float* __restrict__ ws) {
    if (blockIdx.x == 384) {
        int k = threadIdx.x;
        if (k < HH) {
            float u1 = 0.f, u2 = 0.f;
            for (int j = 0; j < HH; j++) {
                float w = Wt[j * HH + k];
                u1 = fmaf(w, a[j], u1);
                u2 = fmaf(w, a[HH + j], u2);
            }
            ws[U1O + k] = u1;
            ws[U2O + k] = u2;
            if (k == 0) {
                float c1 = 0.f, c2 = 0.f;
                for (int j = 0; j < HH; j++) {
                    c1 = fmaf(bt[j], a[j], c1);
                    c2 = fmaf(bt[j], a[HH + j], c2);
                }
                ws[CCO] = c1;
                ws[CCO + 1] = c2;
                ((unsigned*)ws)[CCO + 2] = fenc_(-1e30f);
            }
        }
        return;
    }
    int o = blockIdx.x * 256 + threadIdx.x;  // 0 .. 98304
    _Float16* wf = (_Float16*)(ws + WFRG);
    if (o < 98304) {
        int j = o & 7;
        int lane = (o >> 3) & 63;
        int rest = o >> 9;           // 0..191
        int ks = rest % 6;
        int gw = rest / 6;           // w*4 + g
        int g = gw & 3, w = gw >> 2;
        int col = g * 128 + w * 16 + (lane & 15);
        int k = ks * 32 + (lane >> 4) * 8 + j;
        float v = (k < DD) ? Wih[col * DD + k] : Whh[col * HH + (k - DD)];
        wf[o] = (_Float16)v;
    }
    if (o < GG) ws[BSUM + o] = bih[o] + bhh[o];
    if (o < 392) ws[SSUM + o] = 0.f;   // sums + counters
}

// ---- BN1 stats: 1024 blocks, float4 rows, atomics + last-block finalize ----
__global__ __launch_bounds__(256) void k_bn1_stats(const float* __restrict__ x,
                                                   const float* __restrict__ g1,
                                                   const float* __restrict__ b1,
                                                   float* __restrict__ ws) {
    int tid = threadIdx.x;
    int d = tid & 63;
    int n = blockIdx.x * 4 + (tid >> 6);
    const float4* xr = (const float4*)(x + ((size_t)n * DD + d) * TT);
    float s = 0.f, ss = 0.f;
#pragma unroll
    for (int q = 0; q < 15; q++) {
        float4 v = xr[q];
        s += v.x + v.y + v.z + v.w;
        ss = fmaf(v.x, v.x, fmaf(v.y, v.y, fmaf(v.z, v.z, fmaf(v.w, v.w, ss))));
    }
    __shared__ float rs[256], rss[256];
    __shared__ unsigned done;
    rs[tid] = s; rss[tid] = ss;
    __syncthreads();
    if (tid < 64) {
        float ts = rs[tid] + rs[64 + tid] + rs[128 + tid] + rs[192 + tid];
        float tss = rss[tid] + rss[64 + tid] + rss[128 + tid] + rss[192 + tid];
        atomicAdd(&ws[SSUM + tid], ts);
        atomicAdd(&ws[SSUM + 64 + tid], tss);
    }
    __syncthreads();
    if (tid == 0) {
        __threadfence();
        done = atomicAdd((unsigned*)(ws + SSUM) + 128, 1u);
    }
    __syncthreads();
    if (done == 1023u) {
        __threadfence();
        if (tid < 64) {
            float cnt = (float)(NN * TT);
            float m = ws[SSUM + tid] / cnt;
            float var = ws[SSUM + 64 + tid] / cnt - m * m;
            float sc = g1[tid] * rsqrtf(var + 1e-5f);
            ws[SC1 + tid] = sc;
            ws[SH1 + tid] = b1[tid] - m * sc;
        }
    }
}

// ---- BN1 apply + transpose to half xnT[t][n][d] ----
__global__ void k_bn1_apply(const float* __restrict__ x, float* __restrict__ ws) {
    int n = blockIdx.x, tid = threadIdx.x;
    __shared__ float lx[DD * 61];
    __shared__ float sc[DD], sh[DD];
    if (tid < DD) { sc[tid] = ws[SC1 + tid]; sh[tid] = ws[SH1 + tid]; }
    const float4* xr4 = (const float4*)(x + (size_t)n * DD * TT);
    for (int i = tid; i < 960; i += 256) {
        int d = i / 15, q = i - d * 15;
        float4 v = xr4[i];
        float* p = &lx[d * 61 + q * 4];
        p[0] = v.x; p[1] = v.y; p[2] = v.z; p[3] = v.w;
    }
    __syncthreads();
    _Float16* out = (_Float16*)ws;  // XNT
    for (int i = tid; i < TT * DD; i += 256) {
        int t = i >> 6, d = i & 63;
        out[((size_t)t * NN + n) * DD + d] = (_Float16)fmaf(lx[d * 61 + t], sc[d], sh[d]);
    }
}

// ---- LSTM: MFMA, weights persistent in VGPRs; 8 waves/block -> 2 waves/SIMD ----
// wave w owns hidden cols [w*16, w*16+16); 256 blocks x 16 rows
__global__ __launch_bounds__(512, 1) void k_lstm(float* __restrict__ ws) {
    int tid = threadIdx.x;
    int w = tid >> 6, lane = tid & 63;
    int quad = lane >> 4, m = lane & 15;
    int r0 = blockIdx.x * 16;
    __shared__ _Float16 hlds[2][16][136];
    const _Float16* wf = (const _Float16*)(ws + WFRG);

    h8 bw[4][6];
#pragma unroll
    for (int g = 0; g < 4; g++)
#pragma unroll
        for (int ks = 0; ks < 6; ks++)
            bw[g][ks] = *(const h8*)(wf + ((((w * 4 + g) * 6 + ks) * 64 + lane) * 8));

    float bias[4];
#pragma unroll
    for (int g = 0; g < 4; g++) bias[g] = ws[BSUM + g * 128 + w * 16 + m];

    for (int p = tid; p < 2 * 16 * 136; p += 512) ((_Float16*)hlds)[p] = (_Float16)0.f;

    f4 cst = {};
    float hv[4];
    const _Float16* xb = (const _Float16*)ws + (size_t)(r0 + m) * DD + quad * 8;
    __syncthreads();

    h8 ax0 = *(const h8*)xb;
    h8 ax1 = *(const h8*)(xb + 32);

    for (int t = 0; t < TT; t++) {
        h8 ah[4];
        const _Float16* hb = &hlds[(t + 1) & 1][m][quad * 8];
#pragma unroll
        for (int ks = 0; ks < 4; ks++) ah[ks] = *(const h8*)(hb + ks * 32);
        h8 nx0 = {}, nx1 = {};
        if (t + 1 < TT) {
            const _Float16* xp = xb + (size_t)(t + 1) * NN * DD;
            nx0 = *(const h8*)xp;
            nx1 = *(const h8*)(xp + 32);
        }

        f4 acc[4];
#pragma unroll
        for (int g = 0; g < 4; g++) acc[g] = (f4){bias[g], bias[g], bias[g], bias[g]};
#pragma unroll
        for (int g = 0; g < 4; g++) acc[g] = __builtin_amdgcn_mfma_f32_16x16x32_f16(ax0, bw[g][0], acc[g], 0, 0, 0);
#pragma unroll
        for (int g = 0; g < 4; g++) acc[g] = __builtin_amdgcn_mfma_f32_16x16x32_f16(ax1, bw[g][1], acc[g], 0, 0, 0);
#pragma unroll
        for (int ks = 0; ks < 4; ks++)
#pragma unroll
            for (int g = 0; g < 4; g++)
                acc[g] = __builtin_amdgcn_mfma_f32_16x16x32_f16(ah[ks], bw[g][ks + 2], acc[g], 0, 0, 0);

#pragma unroll
        for (int r = 0; r < 4; r++) {
            float ig = sigmoidf_(acc[0][r]);
            float fg = sigmoidf_(acc[1][r]);
            float gg = tanhfast_(acc[2][r]);
            float og = sigmoidf_(acc[3][r]);
            float c = fmaf(fg, cst[r], ig * gg);
            cst[r] = c;
            hv[r] = og * tanhfast_(c);
        }
        _Float16* wbuf = &hlds[t & 1][0][0];
        int col = w * 16 + m;
#pragma unroll
        for (int r = 0; r < 4; r++) wbuf[(quad * 4 + r) * 136 + col] = (_Float16)hv[r];
        __syncthreads();
        ax0 = nx0; ax1 = nx1;
    }
    int col = w * 16 + m;
#pragma unroll
    for (int r = 0; r < 4; r++)
        ws[HID + (size_t)(r0 + quad * 4 + r) * HH + col] = hv[r];
}

// ---- BN2 stats: 64 blocks, coalesced reads, atomics + last-block finalize ----
__global__ __launch_bounds__(256) void k_bn2_stats(const float* __restrict__ g2,
                                                   const float* __restrict__ b2,
                                                   float* __restrict__ ws) {
    int tid = threadIdx.x;
    int col = tid & 127, grp = tid >> 7;
    int r0 = blockIdx.x * 64 + grp * 32;
    float s = 0.f, ss = 0.f;
    const float* hp = ws + HID + (size_t)r0 * HH + col;
#pragma unroll 4
    for (int rr = 0; rr < 32; rr++) {
        float v = hp[rr * HH];
        s += v;
        ss = fmaf(v, v, ss);
    }
    __shared__ float rs[256], rss[256];
    __shared__ unsigned done;
    rs[tid] = s; rss[tid] = ss;
    __syncthreads();
    if (tid < 128) {
        atomicAdd(&ws[SSUM + 132 + tid], rs[tid] + rs[128 + tid]);
        atomicAdd(&ws[SSUM + 260 + tid], rss[tid] + rss[128 + tid]);
    }
    __syncthreads();
    if (tid == 0) {
        __threadfence();
        done = atomicAdd((unsigned*)(ws + SSUM) + 129, 1u);
    }
    __syncthreads();
    if (done == 63u) {
        __threadfence();
        if (tid < 128) {
            float m = ws[SSUM + 132 + tid] / (float)NN;
            float var = ws[SSUM + 260 + tid] / (float)NN - m * m;
            float sc = g2[tid] * rsqrtf(var + 1e-5f);
            ws[SC2 + tid] = sc;
            ws[SH2 + tid] = b2[tid] - m * sc;
        }
    }
}

// ---- apply BN2: s1, s2, fp32 hbn, LDS-staged coalesced swizzled fp16 hbn, s1max ----
__global__ void k_hbn(float* __restrict__ ws) {
    __shared__ float sc[HH], sh[HH], u1s[HH], u2s[HH];
    __shared__ _Float16 swz[4096];  // one 8KB slab: [hg][lane_s][jj]
    int tid = threadIdx.x;
    if (tid < HH) {
        sc[tid] = ws[SC2 + tid]; sh[tid] = ws[SH2 + tid];
        u1s[tid] = ws[U1O + tid]; u2s[tid] = ws[U2O + tid];
    }
    __syncthreads();
    int r = tid >> 3, l = tid & 7;
    int n = blockIdx.x * 32 + r;
    const float* hr = ws + HID + (size_t)n * HH;
    float* hb = ws + HBN + (size_t)n * HH;
    int lanehi = (r >> 3);       // (n>>3)&3 == r>>3 since n = blk*32 + r
    int jj = r & 7;              // n & 7
    float d1 = 0.f, d2 = 0.f;
    int k0 = l * 16;
#pragma unroll
    for (int q4 = 0; q4 < 4; q4++) {
        float4 hv4 = *(const float4*)&hr[k0 + q4 * 4];
        float4 o;
#pragma unroll
        for (int c = 0; c < 4; c++) {
            int kk = k0 + q4 * 4 + c;
            float v = fmaf(((const float*)&hv4)[c], sc[kk], sh[kk]);
            ((float*)&o)[c] = v;
            // swz idx: hg=l, lane_s = lanehi*16 + (kk&15)
            swz[l * 512 + (lanehi * 16 + (kk & 15)) * 8 + jj] = (_Float16)v;
            d1 = fmaf(v, u1s[kk], d1);
            d2 = fmaf(v, u2s[kk], d2);
        }
        *(float4*)&hb[k0 + q4 * 4] = o;
    }
#pragma unroll
    for (int o = 1; o < 8; o <<= 1) { d1 += __shfl_xor(d1, o, 64); d2 += __shfl_xor(d2, o, 64); }
    if (l == 0) {
        float s1 = d1 + ws[CCO];
        ws[S1O + n] = s1;
        ws[S2O + n] = d2 + ws[CCO + 1];
        atomicMax((unsigned*)ws + CCO + 2, fenc_(s1));
    }
    __syncthreads();
    // coalesced copy-out of the block's slab
    _Float16* dst = (_Float16*)ws + (size_t)blockIdx.x * 4096;
    for (int p = tid; p < 512; p += 256)
        *(h8*)(dst + p * 8) = *(const h8*)(swz + p * 8);
}

// ---- attention: MFMA flash-style; 512 blocks (16 rows x 4 hgroups each) ----
__global__ __launch_bounds__(256, 1) void k_att(float* __restrict__ ws) {
    __shared__ float ls1[NN];
    __shared__ float rowsum[16];
    int tid = threadIdx.x;
    int w = tid >> 6, lane = tid & 63;
    int quad = lane >> 4, m = lane & 15;
    int bb = blockIdx.x & 255, ch = blockIdx.x >> 8;
    int n0 = bb * 16;
    for (int i = tid; i < NN; i += 256) ls1[i] = ws[S1O + i];
    __syncthreads();
    float s1max = fdec_(((unsigned*)ws)[CCO + 2]);
    float s2n = ws[S2O + n0 + m];
    float mi = leakyf_(s2n + s1max);
    const _Float16* hbsw = (const _Float16*)ws;
    int hg = ch * 4 + w;
    f4 acc = {};
    float psum = 0.f;
    h8 bcur = *(const h8*)(hbsw + ((size_t)(0 * 8 + hg) * 64 + lane) * 8);
    for (int jt = 0; jt < 128; jt++) {
        const float* sp = &ls1[jt * 32 + quad * 8];
        h8 ap;
        float ps = 0.f;
#pragma unroll
        for (int jj = 0; jj < 8; jj++) {
            float z = s2n + sp[jj];
            float p = __expf(leakyf_(z) - mi);
            ps += p;
            ap[jj] = (_Float16)p;
        }
        psum += ps;
        int jn = (jt + 1 < 128) ? jt + 1 : 127;
        h8 bnext = *(const h8*)(hbsw + ((size_t)(jn * 8 + hg) * 64 + lane) * 8);
        acc = __builtin_amdgcn_mfma_f32_16x16x32_f16(ap, bcur, acc, 0, 0, 0);
        bcur = bnext;
    }
    psum += __shfl_xor(psum, 16, 64);
    psum += __shfl_xor(psum, 32, 64);
    if (w == 0 && lane < 16) rowsum[lane] = psum;
    __syncthreads();
    float invs[4];
#pragma unroll
    for (int r = 0; r < 4; r++) invs[r] = 1.f / rowsum[quad * 4 + r];
    int h = hg * 16 + m;
#pragma unroll
    for (int r = 0; r < 4; r++) {
        int n = n0 + quad * 4 + r;
        ws[H2O + (size_t)n * HH + h] = fmaf(acc[r], invs[r], ws[HBN + (size_t)n * HH + h]);
    }
}

// ---- final fc + leaky + out projection + sigmoid ----
__global__ __launch_bounds__(256) void k_fc(const float* __restrict__ Wfc, const float* __restrict__ bfc,
                                            const float* __restrict__ Wout, const float* __restrict__ bout,
                                            float* __restrict__ ws, float* __restrict__ out) {
    __shared__ float h2r[32][HH + 4];
    int tid = threadIdx.x;
    int n0 = blockIdx.x * 32;
    for (int p = tid; p < 32 * HH; p += 256) h2r[p >> 7][p & 127] = ws[H2O + (size_t)n0 * HH + p];
    __syncthreads();
    int r = tid >> 3, l = tid & 7;
    int n = n0 + r;
    float po = 0.f;
    for (int jj = 0; jj < 16; jj++) {
        int j = l * 16 + jj;
        const float4* wrow = (const float4*)(Wfc + (size_t)j * HH);
        float acc = 0.f;
#pragma unroll 8
        for (int q = 0; q < 32; q++) {
            float4 wv = wrow[q];
            float4 hv = *(const float4*)&h2r[r][q * 4];
            acc = fmaf(wv.x, hv.x, fmaf(wv.y, hv.y, fmaf(wv.z, hv.z, fmaf(wv.w, hv.w, acc))));
        }
        float h3 = leakyf_(acc + bfc[j]);
        po = fmaf(h3, Wout[j], po);
    }
#pragma unroll
    for (int o = 1; o < 8; o <<= 1) po += __shfl_xor(po, o, 64);
    if (l == 0) out[n] = 1.f / (1.f + __expf(-(po + bout[0])));
}

extern "C" void kernel_launch(void* const* d_in, const int* in_sizes, int n_in,
                              void* d_out, int out_size, void* d_ws, size_t ws_size,
                              hipStream_t stream) {
    const float* x = (const float*)d_in[0];
    const float* bn1_g = (const float*)d_in[1];
    const float* bn1_b = (const float*)d_in[2];
    const float* W_ih = (const float*)d_in[3];
    const float* W_hh = (const float*)d_in[4];
    const float* b_ih = (const float*)d_in[5];
    const float* b_hh = (const float*)d_in[6];
    const float* bn2_g = (const float*)d_in[7];
    const float* bn2_b = (const float*)d_in[8];
    const float* W_t = (const float*)d_in[9];
    const float* b_t = (const float*)d_in[10];
    const float* a = (const float*)d_in[11];
    const float* W_fc = (const float*)d_in[12];
    const float* b_fc = (const float*)d_in[13];
    const float* W_out = (const float*)d_in[14];
    const float* b_out = (const float*)d_in[15];
    float* ws = (float*)d_ws;
    float* out = (float*)d_out;

    k_prep<<<385, 256, 0, stream>>>(W_ih, W_hh, b_ih, b_hh, W_t, b_t, a, ws);
    k_bn1_stats<<<NN / 4, 256, 0, stream>>>(x, bn1_g, bn1_b, ws);
    k_bn1_apply<<<NN, 256, 0, stream>>>(x, ws);
    k_lstm<<<NN / 16, 512, 0, stream>>>(ws);
    k_bn2_stats<<<64, 256, 0, stream>>>(bn2_g, bn2_b, ws);
    k_hbn<<<NN / 32, 256, 0, stream>>>(ws);
    k_att<<<512, 256, 0, stream>>>(ws);
    k_fc<<<NN / 32, 256, 0, stream>>>(W_fc, b_fc, W_out, b_out, ws, out);
}

// Round 6
// 398.349 us; speedup vs baseline: 1.0285x; 1.0285x over previous
//
#include <hip/hip_runtime.h>
#include <math.h>

constexpr int NN = 4096, DD = 64, TT = 60, HH = 128, GG = 512, KK = 192;

typedef _Float16 h8 __attribute__((ext_vector_type(8)));
typedef float f4 __attribute__((ext_vector_type(4)));

// ws layout (float offsets)
constexpr size_t XNT = 0;                                  // half [T][N][D] RAW x fp16; REUSED later as swizzled hbn16
constexpr size_t WFRG = (size_t)TT * NN * DD / 2;          // half [w][g][ks][lane][8] = 98304 halves
constexpr size_t BSUM = WFRG + 98304 / 2;                  // [512] f32 (bias incl. BN1 shift fold)
constexpr size_t SC1 = BSUM + GG;                          // [64]
constexpr size_t SH1 = SC1 + DD;                           // [64]
constexpr size_t HID = SH1 + DD;                           // [N][H] f32
constexpr size_t HBN = HID + (size_t)NN * HH;              // [N][H]
constexpr size_t SC2 = HBN + (size_t)NN * HH;              // [128]
constexpr size_t SH2 = SC2 + HH;
constexpr size_t U1O = SH2 + HH;
constexpr size_t U2O = U1O + HH;
constexpr size_t CCO = U2O + HH;                           // [4]: c1, c2, s1max(encoded uint)
constexpr size_t S1O = CCO + 4;                            // [N]
constexpr size_t S2O = S1O + NN;
constexpr size_t H2O = S2O + NN;                           // [N][H]
constexpr size_t SSUM = H2O + (size_t)NN * HH;             // [0:64) bn1 sum, [64:128) bn1 sumsq,
                                                           // 128 bn1 ctr, 129 bn2 ctr,
                                                           // [132:260) bn2 sum, [260:388) bn2 sumsq

__device__ __forceinline__ float sigmoidf_(float x) { return 1.f / (1.f + __expf(-x)); }
__device__ __forceinline__ float tanhfast_(float x) { return 1.f - 2.f / (__expf(2.f * x) + 1.f); }
__device__ __forceinline__ float leakyf_(float z) { return fmaxf(z, 0.01f * z); }

__device__ __forceinline__ unsigned fenc_(float f) {
    unsigned b = __float_as_uint(f);
    return (b & 0x80000000u) ? ~b : (b | 0x80000000u);
}
__device__ __forceinline__ float fdec_(unsigned u) {
    return (u & 0x80000000u) ? __uint_as_float(u & 0x7fffffffu) : __uint_as_float(~u);
}

// ---- fused BN1 stats + fp16 transpose (ONE pass over x) ----
// 1024 blocks x 256 thr; block handles rows n0..n0+3, thread (r,d) owns x[n][d][:]
__global__ __launch_bounds__(256) void k_xstats(const float* __restrict__ x,
                                                const float* __restrict__ g1,
                                                const float* __restrict__ b1,
                                                float* __restrict__ ws) {
    int tid = threadIdx.x;
    int r = tid >> 6, d = tid & 63;
    int n0 = blockIdx.x * 4;
    __shared__ _Float16 stg[TT * 4 * 64];   // [t][r][d] = 30720 B
    __shared__ float rs[256], rss[256];
    __shared__ unsigned done;
    const float4* xr = (const float4*)(x + ((size_t)(n0 + r) * DD + d) * TT);
    float s = 0.f, ss = 0.f;
#pragma unroll
    for (int q = 0; q < 15; q++) {
        float4 v = xr[q];
        s += v.x + v.y + v.z + v.w;
        ss = fmaf(v.x, v.x, fmaf(v.y, v.y, fmaf(v.z, v.z, fmaf(v.w, v.w, ss))));
        int t = q * 4;
        _Float16* sp = &stg[(size_t)t * 256 + r * 64 + d];
        sp[0] = (_Float16)v.x; sp[256] = (_Float16)v.y;
        sp[512] = (_Float16)v.z; sp[768] = (_Float16)v.w;
    }
    rs[tid] = s; rss[tid] = ss;
    __syncthreads();
    if (tid < 64) {
        float ts = rs[tid] + rs[64 + tid] + rs[128 + tid] + rs[192 + tid];
        float tss = rss[tid] + rss[64 + tid] + rss[128 + tid] + rss[192 + tid];
        atomicAdd(&ws[SSUM + tid], ts);
        atomicAdd(&ws[SSUM + 64 + tid], tss);
    }
    __syncthreads();
    if (tid == 0) {
        __threadfence();
        done = atomicAdd((unsigned*)(ws + SSUM) + 128, 1u);
    }
    __syncthreads();
    if (done == 1023u) {
        __threadfence();
        if (tid < 64) {
            float cnt = (float)(NN * TT);
            float m = ws[SSUM + tid] / cnt;
            float var = ws[SSUM + 64 + tid] / cnt - m * m;
            float sc = g1[tid] * rsqrtf(var + 1e-5f);
            ws[SC1 + tid] = sc;
            ws[SH1 + tid] = b1[tid] - m * sc;
        }
    }
    // coalesced copy-out: xnT[t][n0..n0+3][0..63] = 60 chunks of 512B
    _Float16* out = (_Float16*)ws;  // XNT
    for (int p = tid; p < 1920; p += 256) {
        int t = p >> 5, i = p & 31;
        *(h8*)(out + ((size_t)t * NN + n0) * DD + i * 8) = *(const h8*)(stg + p * 8);
    }
}

// ---- prep (fused): weight swizzle (BN1 scale folded) + bias fold + u/v vectors ----
// frag (w,g,ks): value = W[k][col]*fold, col = g*128 + w*16 + (lane&15), k = ks*32 + (lane>>4)*8 + j
__global__ void k_prep(const float* __restrict__ Wih, const float* __restrict__ Whh,
                       const float* __restrict__ bih, const float* __restrict__ bhh,
                       const float* __restrict__ Wt, const float* __restrict__ bt,
                       const float* __restrict__ a, float* __restrict__ ws) {
    if (blockIdx.x == 384) {
        int k = threadIdx.x;
        if (k < HH) {
            float u1 = 0.f, u2 = 0.f;
            for (int j = 0; j < HH; j++) {
                float w = Wt[j * HH + k];
                u1 = fmaf(w, a[j], u1);
                u2 = fmaf(w, a[HH + j], u2);
            }
            ws[U1O + k] = u1;
            ws[U2O + k] = u2;
            if (k == 0) {
                float c1 = 0.f, c2 = 0.f;
                for (int j = 0; j < HH; j++) {
                    c1 = fmaf(bt[j], a[j], c1);
                    c2 = fmaf(bt[j], a[HH + j], c2);
                }
                ws[CCO] = c1;
                ws[CCO + 1] = c2;
                ((unsigned*)ws)[CCO + 2] = fenc_(-1e30f);
            }
        }
        return;
    }
    if (blockIdx.x == 385) {
        // bias fold: b' = bih + bhh + Wih @ sh1
        int c0 = threadIdx.x * 2;
#pragma unroll
        for (int c = c0; c < c0 + 2; c++) {
            float acc = bih[c] + bhh[c];
            for (int d = 0; d < DD; d++) acc = fmaf(Wih[c * DD + d], ws[SH1 + d], acc);
            ws[BSUM + c] = acc;
        }
        return;
    }
    int o = blockIdx.x * 256 + threadIdx.x;  // 0 .. 98304
    _Float16* wf = (_Float16*)(ws + WFRG);
    if (o < 98304) {
        int j = o & 7;
        int lane = (o >> 3) & 63;
        int rest = o >> 9;           // 0..191
        int ks = rest % 6;
        int gw = rest / 6;           // w*4 + g
        int g = gw & 3, w = gw >> 2;
        int col = g * 128 + w * 16 + (lane & 15);
        int k = ks * 32 + (lane >> 4) * 8 + j;
        float v = (k < DD) ? Wih[col * DD + k] * ws[SC1 + k] : Whh[col * HH + (k - DD)];
        wf[o] = (_Float16)v;
    }
}

// ---- LSTM: MFMA, weights persistent in VGPRs; 8 waves/block -> 2 waves/SIMD ----
// wave w owns hidden cols [w*16, w*16+16); 256 blocks x 16 rows
__global__ __launch_bounds__(512, 1) void k_lstm(float* __restrict__ ws) {
    int tid = threadIdx.x;
    int w = tid >> 6, lane = tid & 63;
    int quad = lane >> 4, m = lane & 15;
    int r0 = blockIdx.x * 16;
    __shared__ _Float16 hlds[2][16][136];
    const _Float16* wf = (const _Float16*)(ws + WFRG);

    h8 bw[4][6];
#pragma unroll
    for (int g = 0; g < 4; g++)
#pragma unroll
        for (int ks = 0; ks < 6; ks++)
            bw[g][ks] = *(const h8*)(wf + ((((w * 4 + g) * 6 + ks) * 64 + lane) * 8));

    float bias[4];
#pragma unroll
    for (int g = 0; g < 4; g++) bias[g] = ws[BSUM + g * 128 + w * 16 + m];

    for (int p = tid; p < 2 * 16 * 136; p += 512) ((_Float16*)hlds)[p] = (_Float16)0.f;

    f4 cst = {};
    float hv[4];
    const _Float16* xb = (const _Float16*)ws + (size_t)(r0 + m) * DD + quad * 8;
    __syncthreads();

    h8 ax0 = *(const h8*)xb;
    h8 ax1 = *(const h8*)(xb + 32);

    for (int t = 0; t < TT; t++) {
        h8 ah[4];
        const _Float16* hb = &hlds[(t + 1) & 1][m][quad * 8];
#pragma unroll
        for (int ks = 0; ks < 4; ks++) ah[ks] = *(const h8*)(hb + ks * 32);
        h8 nx0 = {}, nx1 = {};
        if (t + 1 < TT) {
            const _Float16* xp = xb + (size_t)(t + 1) * NN * DD;
            nx0 = *(const h8*)xp;
            nx1 = *(const h8*)(xp + 32);
        }

        f4 acc[4];
#pragma unroll
        for (int g = 0; g < 4; g++) acc[g] = (f4){bias[g], bias[g], bias[g], bias[g]};
#pragma unroll
        for (int g = 0; g < 4; g++) acc[g] = __builtin_amdgcn_mfma_f32_16x16x32_f16(ax0, bw[g][0], acc[g], 0, 0, 0);
#pragma unroll
        for (int g = 0; g < 4; g++) acc[g] = __builtin_amdgcn_mfma_f32_16x16x32_f16(ax1, bw[g][1], acc[g], 0, 0, 0);
#pragma unroll
        for (int ks = 0; ks < 4; ks++)
#pragma unroll
            for (int g = 0; g < 4; g++)
                acc[g] = __builtin_amdgcn_mfma_f32_16x16x32_f16(ah[ks], bw[g][ks + 2], acc[g], 0, 0, 0);

#pragma unroll
        for (int r = 0; r < 4; r++) {
            float ig = sigmoidf_(acc[0][r]);
            float fg = sigmoidf_(acc[1][r]);
            float gg = tanhfast_(acc[2][r]);
            float og = sigmoidf_(acc[3][r]);
            float c = fmaf(fg, cst[r], ig * gg);
            cst[r] = c;
            hv[r] = og * tanhfast_(c);
        }
        _Float16* wbuf = &hlds[t & 1][0][0];
        int col = w * 16 + m;
#pragma unroll
        for (int r = 0; r < 4; r++) wbuf[(quad * 4 + r) * 136 + col] = (_Float16)hv[r];
        __syncthreads();
        ax0 = nx0; ax1 = nx1;
    }
    int col = w * 16 + m;
#pragma unroll
    for (int r = 0; r < 4; r++)
        ws[HID + (size_t)(r0 + quad * 4 + r) * HH + col] = hv[r];
}

// ---- BN2 stats: 64 blocks, coalesced reads, atomics + last-block finalize ----
__global__ __launch_bounds__(256) void k_bn2_stats(const float* __restrict__ g2,
                                                   const float* __restrict__ b2,
                                                   float* __restrict__ ws) {
    int tid = threadIdx.x;
    int col = tid & 127, grp = tid >> 7;
    int r0 = blockIdx.x * 64 + grp * 32;
    float s = 0.f, ss = 0.f;
    const float* hp = ws + HID + (size_t)r0 * HH + col;
#pragma unroll 4
    for (int rr = 0; rr < 32; rr++) {
        float v = hp[rr * HH];
        s += v;
        ss = fmaf(v, v, ss);
    }
    __shared__ float rs[256], rss[256];
    __shared__ unsigned done;
    rs[tid] = s; rss[tid] = ss;
    __syncthreads();
    if (tid < 128) {
        atomicAdd(&ws[SSUM + 132 + tid], rs[tid] + rs[128 + tid]);
        atomicAdd(&ws[SSUM + 260 + tid], rss[tid] + rss[128 + tid]);
    }
    __syncthreads();
    if (tid == 0) {
        __threadfence();
        done = atomicAdd((unsigned*)(ws + SSUM) + 129, 1u);
    }
    __syncthreads();
    if (done == 63u) {
        __threadfence();
        if (tid < 128) {
            float m = ws[SSUM + 132 + tid] / (float)NN;
            float var = ws[SSUM + 260 + tid] / (float)NN - m * m;
            float sc = g2[tid] * rsqrtf(var + 1e-5f);
            ws[SC2 + tid] = sc;
            ws[SH2 + tid] = b2[tid] - m * sc;
        }
    }
}

// ---- apply BN2: s1, s2, fp32 hbn, LDS-staged coalesced swizzled fp16 hbn, s1max ----
__global__ void k_hbn(float* __restrict__ ws) {
    __shared__ float sc[HH], sh[HH], u1s[HH], u2s[HH];
    __shared__ _Float16 swz[4096];  // one 8KB slab: [hg][lane_s][jj]
    int tid = threadIdx.x;
    if (tid < HH) {
        sc[tid] = ws[SC2 + tid]; sh[tid] = ws[SH2 + tid];
        u1s[tid] = ws[U1O + tid]; u2s[tid] = ws[U2O + tid];
    }
    __syncthreads();
    int r = tid >> 3, l = tid & 7;
    int n = blockIdx.x * 32 + r;
    const float* hr = ws + HID + (size_t)n * HH;
    float* hb = ws + HBN + (size_t)n * HH;
    int lanehi = (r >> 3);
    int jj = r & 7;
    float d1 = 0.f, d2 = 0.f;
    int k0 = l * 16;
#pragma unroll
    for (int q4 = 0; q4 < 4; q4++) {
        float4 hv4 = *(const float4*)&hr[k0 + q4 * 4];
        float4 o;
#pragma unroll
        for (int c = 0; c < 4; c++) {
            int kk = k0 + q4 * 4 + c;
            float v = fmaf(((const float*)&hv4)[c], sc[kk], sh[kk]);
            ((float*)&o)[c] = v;
            swz[l * 512 + (lanehi * 16 + (kk & 15)) * 8 + jj] = (_Float16)v;
            d1 = fmaf(v, u1s[kk], d1);
            d2 = fmaf(v, u2s[kk], d2);
        }
        *(float4*)&hb[k0 + q4 * 4] = o;
    }
#pragma unroll
    for (int o = 1; o < 8; o <<= 1) { d1 += __shfl_xor(d1, o, 64); d2 += __shfl_xor(d2, o, 64); }
    if (l == 0) {
        float s1 = d1 + ws[CCO];
        ws[S1O + n] = s1;
        ws[S2O + n] = d2 + ws[CCO + 1];
        atomicMax((unsigned*)ws + CCO + 2, fenc_(s1));
    }
    __syncthreads();
    _Float16* dst = (_Float16*)ws + (size_t)blockIdx.x * 4096;
    for (int p = tid; p < 512; p += 256)
        *(h8*)(dst + p * 8) = *(const h8*)(swz + p * 8);
}

// ---- attention: MFMA flash-style; 512 blocks (16 rows x 4 hgroups each) ----
__global__ __launch_bounds__(256, 1) void k_att(float* __restrict__ ws) {
    __shared__ float ls1[NN];
    __shared__ float rowsum[16];
    int tid = threadIdx.x;
    int w = tid >> 6, lane = tid & 63;
    int quad = lane >> 4, m = lane & 15;
    int bb = blockIdx.x & 255, ch = blockIdx.x >> 8;
    int n0 = bb * 16;
    for (int i = tid; i < NN; i += 256) ls1[i] = ws[S1O + i];
    __syncthreads();
    float s1max = fdec_(((unsigned*)ws)[CCO + 2]);
    float s2n = ws[S2O + n0 + m];
    float mi = leakyf_(s2n + s1max);
    const _Float16* hbsw = (const _Float16*)ws;
    int hg = ch * 4 + w;
    f4 acc = {};
    float psum = 0.f;
    h8 bcur = *(const h8*)(hbsw + ((size_t)hg * 64 + lane) * 8);
    for (int jt = 0; jt < 128; jt++) {
        const float* sp = &ls1[jt * 32 + quad * 8];
        h8 ap;
        float ps = 0.f;
#pragma unroll
        for (int jj = 0; jj < 8; jj++) {
            float z = s2n + sp[jj];
            float p = __expf(leakyf_(z) - mi);
            ps += p;
            ap[jj] = (_Float16)p;
        }
        psum += ps;
        int jn = (jt + 1 < 128) ? jt + 1 : 127;
        h8 bnext = *(const h8*)(hbsw + ((size_t)(jn * 8 + hg) * 64 + lane) * 8);
        acc = __builtin_amdgcn_mfma_f32_16x16x32_f16(ap, bcur, acc, 0, 0, 0);
        bcur = bnext;
    }
    psum += __shfl_xor(psum, 16, 64);
    psum += __shfl_xor(psum, 32, 64);
    if (w == 0 && lane < 16) rowsum[lane] = psum;
    __syncthreads();
    float invs[4];
#pragma unroll
    for (int r = 0; r < 4; r++) invs[r] = 1.f / rowsum[quad * 4 + r];
    int h = hg * 16 + m;
#pragma unroll
    for (int r = 0; r < 4; r++) {
        int n = n0 + quad * 4 + r;
        ws[H2O + (size_t)n * HH + h] = fmaf(acc[r], invs[r], ws[HBN + (size_t)n * HH + h]);
    }
}

// ---- final fc + leaky + out projection + sigmoid ----
__global__ __launch_bounds__(256) void k_fc(const float* __restrict__ Wfc, const float* __restrict__ bfc,
                                            const float* __restrict__ Wout, const float* __restrict__ bout,
                                            float* __restrict__ ws, float* __restrict__ out) {
    __shared__ float h2r[32][HH + 4];
    int tid = threadIdx.x;
    int n0 = blockIdx.x * 32;
    for (int p = tid; p < 32 * HH; p += 256) h2r[p >> 7][p & 127] = ws[H2O + (size_t)n0 * HH + p];
    __syncthreads();
    int r = tid >> 3, l = tid & 7;
    int n = n0 + r;
    float po = 0.f;
    for (int jj = 0; jj < 16; jj++) {
        int j = l * 16 + jj;
        const float4* wrow = (const float4*)(Wfc + (size_t)j * HH);
        float acc = 0.f;
#pragma unroll 8
        for (int q = 0; q < 32; q++) {
            float4 wv = wrow[q];
            float4 hv = *(const float4*)&h2r[r][q * 4];
            acc = fmaf(wv.x, hv.x, fmaf(wv.y, hv.y, fmaf(wv.z, hv.z, fmaf(wv.w, hv.w, acc))));
        }
        float h3 = leakyf_(acc + bfc[j]);
        po = fmaf(h3, Wout[j], po);
    }
#pragma unroll
    for (int o = 1; o < 8; o <<= 1) po += __shfl_xor(po, o, 64);
    if (l == 0) out[n] = 1.f / (1.f + __expf(-(po + bout[0])));
}

extern "C" void kernel_launch(void* const* d_in, const int* in_sizes, int n_in,
                              void* d_out, int out_size, void* d_ws, size_t ws_size,
                              hipStream_t stream) {
    const float* x = (const float*)d_in[0];
    const float* bn1_g = (const float*)d_in[1];
    const float* bn1_b = (const float*)d_in[2];
    const float* W_ih = (const float*)d_in[3];
    const float* W_hh = (const float*)d_in[4];
    const float* b_ih = (const float*)d_in[5];
    const float* b_hh = (const float*)d_in[6];
    const float* bn2_g = (const float*)d_in[7];
    const float* bn2_b = (const float*)d_in[8];
    const float* W_t = (const float*)d_in[9];
    const float* b_t = (const float*)d_in[10];
    const float* a = (const float*)d_in[11];
    const float* W_fc = (const float*)d_in[12];
    const float* b_fc = (const float*)d_in[13];
    const float* W_out = (const float*)d_in[14];
    const float* b_out = (const float*)d_in[15];
    float* ws = (float*)d_ws;
    float* out = (float*)d_out;

    hipMemsetAsync((char*)d_ws + SSUM * sizeof(float), 0, 392 * sizeof(float), stream);
    k_xstats<<<NN / 4, 256, 0, stream>>>(x, bn1_g, bn1_b, ws);
    k_prep<<<386, 256, 0, stream>>>(W_ih, W_hh, b_ih, b_hh, W_t, b_t, a, ws);
    k_lstm<<<NN / 16, 512, 0, stream>>>(ws);
    k_bn2_stats<<<64, 256, 0, stream>>>(bn2_g, bn2_b, ws);
    k_hbn<<<NN / 32, 256, 0, stream>>>(ws);
    k_att<<<512, 256, 0, stream>>>(ws);
    k_fc<<<NN / 32, 256, 0, stream>>>(W_fc, b_fc, W_out, b_out, ws, out);
}